// Round 1
// baseline (394.723 us; speedup 1.0000x reference)
//
#include <hip/hip_runtime.h>

#define T_TOK 4096
#define D_DIM 1024
#define F_DIM 2048
#define E_NUM 8

typedef __attribute__((ext_vector_type(8))) short bf16x8;
typedef __attribute__((ext_vector_type(4))) float f32x4;

__device__ __forceinline__ unsigned short f2bf(float f) {
  unsigned u = __builtin_bit_cast(unsigned, f);
  unsigned r = 0x7FFFu + ((u >> 16) & 1u);
  return (unsigned short)((u + r) >> 16);
}

// ---------------- x fp32 -> bf16 ----------------
__global__ __launch_bounds__(256) void cvt_x_kernel(const float* __restrict__ x,
                                                    unsigned short* __restrict__ Xb) {
  int id = blockIdx.x * 256 + threadIdx.x;  // 8 elems per thread, grid sized exactly
  const float4* src = reinterpret_cast<const float4*>(x) + (size_t)id * 2;
  float4 a = src[0], b = src[1];
  uint4 o;
  o.x = f2bf(a.x) | ((unsigned)f2bf(a.y) << 16);
  o.y = f2bf(a.z) | ((unsigned)f2bf(a.w) << 16);
  o.z = f2bf(b.x) | ((unsigned)f2bf(b.y) << 16);
  o.w = f2bf(b.z) | ((unsigned)f2bf(b.w) << 16);
  *reinterpret_cast<uint4*>(Xb + (size_t)id * 8) = o;
}

// ---------------- transpose + convert: src [M][N] fp32 -> dst [N][M] bf16, per expert z ----
__global__ __launch_bounds__(256) void transpose_cvt_kernel(const float* __restrict__ src,
                                                            unsigned short* __restrict__ dst,
                                                            int M, int N) {
  __shared__ float tile[64][65];
  size_t eo = (size_t)blockIdx.z * (size_t)M * (size_t)N;
  src += eo; dst += eo;
  int i0 = blockIdx.y * 64, j0 = blockIdx.x * 64;
  int tid = threadIdx.x;
  #pragma unroll
  for (int r = 0; r < 16; r++) {
    int id = r * 256 + tid;
    int row = id >> 6, col = id & 63;
    tile[row][col] = src[(size_t)(i0 + row) * N + (j0 + col)];
  }
  __syncthreads();
  #pragma unroll
  for (int r = 0; r < 16; r++) {
    int id = r * 256 + tid;
    int orow = id >> 6, ocol = id & 63;
    dst[(size_t)(j0 + orow) * M + (i0 + ocol)] = f2bf(tile[ocol][orow]);
  }
}

// ---------------- router: 1 wave per token ----------------
__global__ __launch_bounds__(256) void router_kernel(const float* __restrict__ x,
                                                     const float* __restrict__ gw,
                                                     int* __restrict__ counts,
                                                     int* __restrict__ list,
                                                     float* __restrict__ wts) {
  int lane = threadIdx.x & 63;
  int t = blockIdx.x * 4 + (threadIdx.x >> 6);
  float acc[E_NUM];
  #pragma unroll
  for (int e = 0; e < E_NUM; e++) acc[e] = 0.f;
  const float* xr = x + (size_t)t * D_DIM;
  #pragma unroll
  for (int j = 0; j < D_DIM / 64; j++) {
    int d = lane + 64 * j;
    float xv = xr[d];
    const float4* g = reinterpret_cast<const float4*>(gw + (size_t)d * E_NUM);
    float4 g0 = g[0], g1 = g[1];
    acc[0] += xv * g0.x; acc[1] += xv * g0.y; acc[2] += xv * g0.z; acc[3] += xv * g0.w;
    acc[4] += xv * g1.x; acc[5] += xv * g1.y; acc[6] += xv * g1.z; acc[7] += xv * g1.w;
  }
  #pragma unroll
  for (int e = 0; e < E_NUM; e++) {
    #pragma unroll
    for (int off = 32; off > 0; off >>= 1) acc[e] += __shfl_xor(acc[e], off);
  }
  if (lane == 0) {
    int e1 = 0; float l1 = acc[0];
    #pragma unroll
    for (int e = 1; e < E_NUM; e++) { if (acc[e] > l1) { l1 = acc[e]; e1 = e; } }
    int e2 = -1; float l2 = -1e30f;
    #pragma unroll
    for (int e = 0; e < E_NUM; e++) { if (e != e1 && acc[e] > l2) { l2 = acc[e]; e2 = e; } }
    float wa = 1.f / (1.f + expf(l2 - l1));
    float wb = 1.f / (1.f + expf(l1 - l2));
    int p1 = atomicAdd(&counts[e1], 1);
    list[e1 * T_TOK + p1] = t * 2;     wts[e1 * T_TOK + p1] = wa;
    int p2 = atomicAdd(&counts[e2], 1);
    list[e2 * T_TOK + p2] = t * 2 + 1; wts[e2 * T_TOK + p2] = wb;
  }
}

// ---------------- GEMM1: H = silu(X@w1) * (X@w3), gathered rows per expert ----------------
__global__ __launch_bounds__(256) void gemm1_kernel(
    const unsigned short* __restrict__ Xb,   // [T][D] bf16
    const unsigned short* __restrict__ W1t,  // [E][F][D] bf16 (transposed)
    const unsigned short* __restrict__ W3t,  // [E][F][D]
    const int* __restrict__ counts, const int* __restrict__ list,
    unsigned short* __restrict__ H) {        // [T*2][F] bf16
  __shared__ unsigned short As[64][72];
  __shared__ unsigned short B1s[128][72];
  __shared__ unsigned short B3s[128][72];
  __shared__ int rid_s[64];

  int e = blockIdx.z;
  int cnt = counts[e];
  int base = blockIdx.y * 64;
  if (base >= cnt) return;
  int nt = blockIdx.x;
  int tid = threadIdx.x;

  if (tid < 64) {
    int r = base + tid; if (r > cnt - 1) r = cnt - 1;
    rid_s[tid] = list[e * T_TOK + r];
  }
  __syncthreads();

  int lane = tid & 63, wid = tid >> 6;
  int wm = (wid >> 1) * 32, wn = (wid & 1) * 64;

  f32x4 acc1[2][4], acc3[2][4];
  #pragma unroll
  for (int mf = 0; mf < 2; mf++)
    #pragma unroll
    for (int nf = 0; nf < 4; nf++) {
      f32x4 z = {0.f, 0.f, 0.f, 0.f};
      acc1[mf][nf] = z; acc3[mf][nf] = z;
    }

  int a_seg = tid & 7, a_row = tid >> 3;
  size_t a_src0 = (size_t)(rid_s[a_row] >> 1) * D_DIM + a_seg * 8;
  size_t a_src1 = (size_t)(rid_s[a_row + 32] >> 1) * D_DIM + a_seg * 8;
  const unsigned short* W1e = W1t + (size_t)e * F_DIM * D_DIM + (size_t)(nt * 128) * D_DIM;
  const unsigned short* W3e = W3t + (size_t)e * F_DIM * D_DIM + (size_t)(nt * 128) * D_DIM;

  for (int k0 = 0; k0 < D_DIM; k0 += 64) {
    *(uint4*)&As[a_row][a_seg * 8]      = *(const uint4*)(Xb + a_src0 + k0);
    *(uint4*)&As[a_row + 32][a_seg * 8] = *(const uint4*)(Xb + a_src1 + k0);
    #pragma unroll
    for (int j = 0; j < 4; j++) {
      int br = j * 32 + (tid >> 3);
      *(uint4*)&B1s[br][a_seg * 8] = *(const uint4*)(W1e + (size_t)br * D_DIM + k0 + a_seg * 8);
      *(uint4*)&B3s[br][a_seg * 8] = *(const uint4*)(W3e + (size_t)br * D_DIM + k0 + a_seg * 8);
    }
    __syncthreads();
    #pragma unroll
    for (int kc = 0; kc < 2; kc++) {
      bf16x8 a[2], b1[4], b3[4];
      int krd = kc * 32 + (lane >> 4) * 8;
      #pragma unroll
      for (int mf = 0; mf < 2; mf++)
        a[mf] = *(const bf16x8*)&As[wm + mf * 16 + (lane & 15)][krd];
      #pragma unroll
      for (int nf = 0; nf < 4; nf++) {
        b1[nf] = *(const bf16x8*)&B1s[wn + nf * 16 + (lane & 15)][krd];
        b3[nf] = *(const bf16x8*)&B3s[wn + nf * 16 + (lane & 15)][krd];
      }
      #pragma unroll
      for (int mf = 0; mf < 2; mf++)
        #pragma unroll
        for (int nf = 0; nf < 4; nf++) {
          acc1[mf][nf] = __builtin_amdgcn_mfma_f32_16x16x32_bf16(a[mf], b1[nf], acc1[mf][nf], 0, 0, 0);
          acc3[mf][nf] = __builtin_amdgcn_mfma_f32_16x16x32_bf16(a[mf], b3[nf], acc3[mf][nf], 0, 0, 0);
        }
    }
    __syncthreads();
  }

  #pragma unroll
  for (int mf = 0; mf < 2; mf++) {
    #pragma unroll
    for (int i = 0; i < 4; i++) {
      int m = wm + mf * 16 + (lane >> 4) * 4 + i;
      if (base + m < cnt) {
        int rid = rid_s[m];
        unsigned short* hrow = H + (size_t)rid * F_DIM + nt * 128;
        #pragma unroll
        for (int nf = 0; nf < 4; nf++) {
          float z = acc1[mf][nf][i];
          float u = acc3[mf][nf][i];
          float hv = (z / (1.f + expf(-z))) * u;
          hrow[wn + nf * 16 + (lane & 15)] = f2bf(hv);
        }
      }
    }
  }
}

// ---------------- GEMM2: out += (H @ w2) * combine_weight ----------------
__global__ __launch_bounds__(256) void gemm2_kernel(
    const unsigned short* __restrict__ H,    // [T*2][F] bf16
    const unsigned short* __restrict__ W2t,  // [E][D][F] bf16 (transposed)
    const int* __restrict__ counts, const int* __restrict__ list,
    const float* __restrict__ wts,
    float* __restrict__ out) {               // [T][D] fp32 (pre-zeroed)
  __shared__ unsigned short As[64][72];
  __shared__ unsigned short Bs[128][72];
  __shared__ int rid_s[64];
  __shared__ float wt_s[64];

  int e = blockIdx.z;
  int cnt = counts[e];
  int base = blockIdx.y * 64;
  if (base >= cnt) return;
  int nt = blockIdx.x;  // 0..7 over D/128
  int tid = threadIdx.x;

  if (tid < 64) {
    int r = base + tid; if (r > cnt - 1) r = cnt - 1;
    rid_s[tid] = list[e * T_TOK + r];
    wt_s[tid] = wts[e * T_TOK + r];
  }
  __syncthreads();

  int lane = tid & 63, wid = tid >> 6;
  int wm = (wid >> 1) * 32, wn = (wid & 1) * 64;

  f32x4 acc[2][4];
  #pragma unroll
  for (int mf = 0; mf < 2; mf++)
    #pragma unroll
    for (int nf = 0; nf < 4; nf++) {
      f32x4 z = {0.f, 0.f, 0.f, 0.f};
      acc[mf][nf] = z;
    }

  int a_seg = tid & 7, a_row = tid >> 3;
  size_t a_src0 = (size_t)rid_s[a_row] * F_DIM + a_seg * 8;
  size_t a_src1 = (size_t)rid_s[a_row + 32] * F_DIM + a_seg * 8;
  const unsigned short* W2e = W2t + (size_t)e * D_DIM * F_DIM + (size_t)(nt * 128) * F_DIM;

  for (int k0 = 0; k0 < F_DIM; k0 += 64) {
    *(uint4*)&As[a_row][a_seg * 8]      = *(const uint4*)(H + a_src0 + k0);
    *(uint4*)&As[a_row + 32][a_seg * 8] = *(const uint4*)(H + a_src1 + k0);
    #pragma unroll
    for (int j = 0; j < 4; j++) {
      int br = j * 32 + (tid >> 3);
      *(uint4*)&Bs[br][a_seg * 8] = *(const uint4*)(W2e + (size_t)br * F_DIM + k0 + a_seg * 8);
    }
    __syncthreads();
    #pragma unroll
    for (int kc = 0; kc < 2; kc++) {
      bf16x8 a[2], b[4];
      int krd = kc * 32 + (lane >> 4) * 8;
      #pragma unroll
      for (int mf = 0; mf < 2; mf++)
        a[mf] = *(const bf16x8*)&As[wm + mf * 16 + (lane & 15)][krd];
      #pragma unroll
      for (int nf = 0; nf < 4; nf++)
        b[nf] = *(const bf16x8*)&Bs[wn + nf * 16 + (lane & 15)][krd];
      #pragma unroll
      for (int mf = 0; mf < 2; mf++)
        #pragma unroll
        for (int nf = 0; nf < 4; nf++)
          acc[mf][nf] = __builtin_amdgcn_mfma_f32_16x16x32_bf16(a[mf], b[nf], acc[mf][nf], 0, 0, 0);
    }
    __syncthreads();
  }

  #pragma unroll
  for (int mf = 0; mf < 2; mf++) {
    #pragma unroll
    for (int i = 0; i < 4; i++) {
      int m = wm + mf * 16 + (lane >> 4) * 4 + i;
      if (base + m < cnt) {
        int tok = rid_s[m] >> 1;
        float w = wt_s[m];
        float* orow = out + (size_t)tok * D_DIM + nt * 128;
        #pragma unroll
        for (int nf = 0; nf < 4; nf++)
          atomicAdd(&orow[wn + nf * 16 + (lane & 15)], acc[mf][nf][i] * w);
      }
    }
  }
}

extern "C" void kernel_launch(void* const* d_in, const int* in_sizes, int n_in,
                              void* d_out, int out_size, void* d_ws, size_t ws_size,
                              hipStream_t stream) {
  const float* x  = (const float*)d_in[0];
  const float* gw = (const float*)d_in[1];
  const float* w1 = (const float*)d_in[2];
  const float* w2 = (const float*)d_in[3];
  const float* w3 = (const float*)d_in[4];
  float* out = (float*)d_out;

  char* ws = (char*)d_ws;
  const size_t LISTB = (size_t)E_NUM * T_TOK * 4;            // 128 KB
  size_t o_counts = 0;
  size_t o_list = 256;
  size_t o_wts  = o_list + LISTB;
  size_t o_Xb   = o_wts + LISTB;                              // 262400
  size_t o_W1t  = o_Xb + (size_t)T_TOK * D_DIM * 2;           // + 8 MB
  size_t wt_sz  = (size_t)E_NUM * F_DIM * D_DIM * 2;          // 33.55 MB each
  size_t o_W3t  = o_W1t + wt_sz;
  size_t o_W2t  = o_W3t + wt_sz;
  size_t o_H    = o_W2t + wt_sz;

  int* counts = (int*)(ws + o_counts);
  int* list   = (int*)(ws + o_list);
  float* wts  = (float*)(ws + o_wts);
  unsigned short* Xb  = (unsigned short*)(ws + o_Xb);
  unsigned short* W1t = (unsigned short*)(ws + o_W1t);
  unsigned short* W3t = (unsigned short*)(ws + o_W3t);
  unsigned short* W2t = (unsigned short*)(ws + o_W2t);
  unsigned short* H   = (unsigned short*)(ws + o_H);

  hipMemsetAsync(counts, 0, 256, stream);
  hipMemsetAsync(out, 0, (size_t)out_size * 4, stream);

  cvt_x_kernel<<<dim3((T_TOK * D_DIM / 8) / 256), 256, 0, stream>>>(x, Xb);

  // w1,w3: [D][F] -> [F][D];  w2: [F][D] -> [D][F]
  transpose_cvt_kernel<<<dim3(F_DIM / 64, D_DIM / 64, E_NUM), 256, 0, stream>>>(w1, W1t, D_DIM, F_DIM);
  transpose_cvt_kernel<<<dim3(F_DIM / 64, D_DIM / 64, E_NUM), 256, 0, stream>>>(w3, W3t, D_DIM, F_DIM);
  transpose_cvt_kernel<<<dim3(D_DIM / 64, F_DIM / 64, E_NUM), 256, 0, stream>>>(w2, W2t, F_DIM, D_DIM);

  router_kernel<<<dim3(T_TOK / 4), 256, 0, stream>>>(x, gw, counts, list, wts);

  gemm1_kernel<<<dim3(F_DIM / 128, T_TOK / 64, E_NUM), 256, 0, stream>>>(
      Xb, W1t, W3t, counts, list, H);
  gemm2_kernel<<<dim3(D_DIM / 128, T_TOK / 64, E_NUM), 256, 0, stream>>>(
      H, W2t, counts, list, wts, out);
}